// Round 1
// baseline (713.465 us; speedup 1.0000x reference)
//
#include <hip/hip_runtime.h>
#include <cstdint>

// TypedTreeCell reduce: per-type TreeLSTM child aggregation.
// N=65536 nodes, K=8 children, H=128, T=4 types.
// out[n] = concat( h_sum[n] @ U_iou[t] + b_iou[t],
//                  sum_k sigmoid(f_input[n] + h[n,k] @ U_f[t] + b_f[t]) * c[n,k] )
//
// R3: single-barrier k_main. The f-gate sigmoid*c reduction is computed
// directly in the MFMA accumulator layout (node=(rbase+rt)*2+(g>>1),
// k=(g&1)*4+r, col=cpair*32+cb*16+lu) with one shfl_xor(16) k-reduce,
// eliminating the f-preact LDS round-trip, two __syncthreads(), the
// ds_write_b16 bank conflicts, and the bf16 rounding of the preacts.

typedef __bf16 bf16;
typedef bf16 bf16x8 __attribute__((ext_vector_type(8)));
typedef bf16 bf16x4 __attribute__((ext_vector_type(4)));
typedef float f32x4 __attribute__((ext_vector_type(4)));

#define N_NODES 65536
#define KCH 8
#define HSZ 128
#define T_TYPES 4
#define TM 16            // nodes per tile
#define LDS_STRIDE 136   // bf16 elems per LDS row (128 + 8 pad)

// ---------------- workspace layout ----------------
// ints: [0..3] counts, [4..7] cursors, [8..11] node offsets,
//       [12..15] tile offsets, [16] total tiles
#define WS_PERM_OFF   256
#define WS_PREUF_OFF  (WS_PERM_OFF + 4*N_NODES)
#define WS_PREUIOU_OFF (WS_PREUF_OFF + 131072)

// ---------------- type histogram ----------------
__global__ void k_count(const int* __restrict__ ta, int* __restrict__ ws_i) {
    int i = blockIdx.x * blockDim.x + threadIdx.x;
    int t = ta[i];
    int lane = threadIdx.x & 63;
    #pragma unroll
    for (int tt = 0; tt < T_TYPES; ++tt) {
        unsigned long long m = __ballot(t == tt);
        int leader = __ffsll((unsigned long long)m) - 1;
        if (t == tt && lane == leader)
            atomicAdd(&ws_i[tt], (int)__popcll(m));
    }
}

__global__ void k_offsets(int* ws_i) {
    if (threadIdx.x == 0 && blockIdx.x == 0) {
        int acc = 0, tacc = 0;
        for (int t = 0; t < T_TYPES; ++t) {
            int cnt = ws_i[t];
            ws_i[8 + t] = acc;    // node offset
            ws_i[4 + t] = acc;    // cursor
            ws_i[12 + t] = tacc;  // tile offset
            acc += cnt;
            tacc += (cnt + TM - 1) / TM;
        }
        ws_i[16] = tacc;
    }
}

__global__ void k_scatter(const int* __restrict__ ta, int* __restrict__ ws_i,
                          int* __restrict__ perm) {
    int i = blockIdx.x * blockDim.x + threadIdx.x;
    int t = ta[i];
    int lane = threadIdx.x & 63;
    #pragma unroll
    for (int tt = 0; tt < T_TYPES; ++tt) {
        unsigned long long m = __ballot(t == tt);
        if (t == tt) {
            int leader = __ffsll((unsigned long long)m) - 1;
            int base = 0;
            if (lane == leader) base = atomicAdd(&ws_i[4 + tt], (int)__popcll(m));
            base = __shfl(base, leader, 64);
            int rank = (int)__popcll(m & ((1ull << lane) - 1ull));
            perm[base + rank] = i;
        }
    }
}

// ---------------- U pre-swizzle into MFMA-B fragment order ----------------
// B frag for 16x16x32 bf16: lane l holds B[k = kblk*32 + (l>>4)*8 + e][col = cb*16 + (l&15)]
// stored as [t][kblk][colblk][lane][e] -> each fragment is one coalesced 16B load.
__global__ void k_swz(const float* __restrict__ Uf, const float* __restrict__ Uiou,
                      bf16* __restrict__ dstf, bf16* __restrict__ dstiou) {
    int idx = blockIdx.x * blockDim.x + threadIdx.x;   // < 262144
    if (idx < T_TYPES * HSZ * HSZ) {
        int t = idx >> 14;
        int r = (idx >> 7) & 127;
        int j = idx & 127;
        float v = Uf[idx];
        int kblk = r >> 5, kin = r & 31;
        int lane = ((kin >> 3) << 4) | (j & 15);
        int e = kin & 7;
        int cb = j >> 4;
        dstf[((((t * 4 + kblk) * 8 + cb) * 64 + lane) << 3) + e] = (bf16)v;
    } else {
        int i2 = idx - T_TYPES * HSZ * HSZ;            // < 4*128*384
        int t = i2 / 49152;
        int rm = i2 - t * 49152;
        int r = rm / 384;
        int j = rm - r * 384;
        float v = Uiou[i2];
        int kblk = r >> 5, kin = r & 31;
        int lane = ((kin >> 3) << 4) | (j & 15);
        int e = kin & 7;
        int cb = j >> 4;
        dstiou[((((t * 4 + kblk) * 24 + cb) * 64 + lane) << 3) + e] = (bf16)v;
    }
}

// ---------------- main fused kernel (512 threads / 16-node tile) ----------------
__global__ __launch_bounds__(512, 6) void k_main(
    const float* __restrict__ h, const float* __restrict__ c,
    const float* __restrict__ f_input,
    const float* __restrict__ b_iou, const float* __restrict__ b_f,
    const int* __restrict__ perm, const int* __restrict__ ws_i,
    const bf16* __restrict__ preUf, const bf16* __restrict__ preUiou,
    float* __restrict__ out)
{
    const int b = blockIdx.x;
    if (b >= ws_i[16]) return;
    int t;
    if (b < ws_i[13]) t = 0;
    else if (b < ws_i[14]) t = 1;
    else if (b < ws_i[15]) t = 2;
    else t = 3;
    const int tile = b - ws_i[12 + t];
    const int cnt = ws_i[t];
    const int base = ws_i[8 + t] + tile * TM;
    const int rem = min(TM, cnt - tile * TM);

    // LDS: 128 child rows + 16 h_sum rows + gn translation cache
    __shared__ __align__(16) bf16 hs[(128 + 16) * LDS_STRIDE];
    __shared__ int gn_lds[TM];
    bf16* hsum = hs + 128 * LDS_STRIDE;

    const int tid = threadIdx.x;
    const int w2 = tid >> 6;       // wave 0..7
    const int l = tid & 63;
    const int lu = l & 15;
    const int g = l >> 4;          // quad group 0..3

    // ---- stage h as bf16 into LDS; per-lane partial h_sum over 4 children ----
    {
        int node = w2 * 2 + (g >> 1);               // node-in-tile 0..15
        int khalf = (g & 1) * 4;
        int mc = node < rem ? node : 0;
        int gn = perm[base + mc];
        if (lu == 0 && (g & 1) == 0) gn_lds[node] = gn;   // stash for epilogues
        const float* hp = h + (long)gn * (KCH * HSZ) + lu * 8;
        float sarr[8];
        #pragma unroll
        for (int i = 0; i < 8; ++i) sarr[i] = 0.f;
        #pragma unroll
        for (int k0 = 0; k0 < 4; ++k0) {
            int k = khalf + k0;
            const float4* p = (const float4*)(hp + k * HSZ);
            float4 a = p[0], bb = p[1];
            sarr[0] += a.x; sarr[1] += a.y; sarr[2] += a.z; sarr[3] += a.w;
            sarr[4] += bb.x; sarr[5] += bb.y; sarr[6] += bb.z; sarr[7] += bb.w;
            bf16x8 v;
            v[0] = (bf16)a.x; v[1] = (bf16)a.y; v[2] = (bf16)a.z; v[3] = (bf16)a.w;
            v[4] = (bf16)bb.x; v[5] = (bf16)bb.y; v[6] = (bf16)bb.z; v[7] = (bf16)bb.w;
            *((bf16x8*)&hs[(node * KCH + k) * LDS_STRIDE + lu * 8]) = v;
        }
        // combine k-halves (lane l <-> l^16)
        #pragma unroll
        for (int i = 0; i < 8; ++i) sarr[i] += __shfl_xor(sarr[i], 16, 64);
        if ((g & 1) == 0) {
            bf16x8 sv;
            #pragma unroll
            for (int i = 0; i < 8; ++i) sv[i] = (bf16)sarr[i];
            *((bf16x8*)&hsum[node * LDS_STRIDE + lu * 8]) = sv;
        }
    }
    __syncthreads();   // the ONLY barrier

    // ---- f-gate GEMM: rows split (w2>>2), cols split (w2&3) across 8 waves ----
    f32x4 acc[4][2];
    #pragma unroll
    for (int rt = 0; rt < 4; ++rt)
        #pragma unroll
        for (int cb = 0; cb < 2; ++cb)
            acc[rt][cb] = (f32x4){0.f, 0.f, 0.f, 0.f};

    const int rbase = (w2 >> 2) * 4;    // row-tile base (0 or 4)
    const int cpair = (w2 & 3);         // 32-col group
    const bf16x8* Bf = (const bf16x8*)preUf;
    #pragma unroll
    for (int kb = 0; kb < 4; ++kb) {
        bf16x8 b0 = Bf[((t * 4 + kb) * 8 + cpair * 2 + 0) * 64 + l];
        bf16x8 b1 = Bf[((t * 4 + kb) * 8 + cpair * 2 + 1) * 64 + l];
        #pragma unroll
        for (int rt = 0; rt < 4; ++rt) {
            bf16x8 a = *((const bf16x8*)&hs[((rbase + rt) * 16 + lu) * LDS_STRIDE + kb * 32 + g * 8]);
            acc[rt][0] = __builtin_amdgcn_mfma_f32_16x16x32_bf16(a, b0, acc[rt][0], 0, 0, 0);
            acc[rt][1] = __builtin_amdgcn_mfma_f32_16x16x32_bf16(a, b1, acc[rt][1], 0, 0, 0);
        }
    }

    // ---- iou GEMM: [16, 128] @ U_iou[t] [128, 384]; 3 col-frags per wave ----
    f32x4 acc2[3];
    #pragma unroll
    for (int cf = 0; cf < 3; ++cf) acc2[cf] = (f32x4){0.f, 0.f, 0.f, 0.f};
    const bf16x8* Bi = (const bf16x8*)preUiou;
    #pragma unroll
    for (int kb = 0; kb < 4; ++kb) {
        bf16x8 a = *((const bf16x8*)&hsum[lu * LDS_STRIDE + kb * 32 + g * 8]);
        #pragma unroll
        for (int cf = 0; cf < 3; ++cf) {
            bf16x8 bfr = Bi[((t * 4 + kb) * 24 + w2 * 3 + cf) * 64 + l];
            acc2[cf] = __builtin_amdgcn_mfma_f32_16x16x32_bf16(a, bfr, acc2[cf], 0, 0, 0);
        }
    }

    // ---- iou epilogue: C/D row = g*4 + r, col = (w2*3+cf)*16 + lu ----
    {
        #pragma unroll
        for (int cf = 0; cf < 3; ++cf) {
            int col = (w2 * 3 + cf) * 16 + lu;
            float bi = b_iou[t * 384 + col];
            #pragma unroll
            for (int r = 0; r < 4; ++r) {
                int m = g * 4 + r;
                if (m < rem)
                    out[(long)gn_lds[m] * (4 * HSZ) + col] = acc2[cf][r] + bi;
            }
        }
    }

    // ---- fused f-gate sigmoid + c reduction, in MFMA accumulator layout ----
    // acc[rt][cb][r] is row rc=(rbase+rt)*16+g*4+r, col=cpair*32+cb*16+lu
    //   -> node=(rbase+rt)*2+(g>>1), k=(g&1)*4+r
    {
        const int col0 = cpair * 32 + lu;
        const float bfv0 = b_f[t * HSZ + col0];
        const float bfv1 = b_f[t * HSZ + col0 + 16];
        const int ghalf = g >> 1;
        const int kbase = (g & 1) * 4;

        int nd[4]; bool ok2[4]; long gns2[4];
        #pragma unroll
        for (int rt = 0; rt < 4; ++rt) {
            nd[rt] = (rbase + rt) * 2 + ghalf;
            ok2[rt] = nd[rt] < rem;
            gns2[rt] = gn_lds[nd[rt]];     // always a valid node index
        }

        #pragma unroll
        for (int rt = 0; rt < 4; ++rt) {
            const float* fr = f_input + gns2[rt] * HSZ + col0;
            float fi0 = fr[0];
            float fi1 = fr[16];
            const float* crow = c + gns2[rt] * (long)(KCH * HSZ) + kbase * HSZ + col0;
            float cv0[4], cv1[4];
            #pragma unroll
            for (int r = 0; r < 4; ++r) {
                cv0[r] = crow[r * HSZ];
                cv1[r] = crow[r * HSZ + 16];
            }
            float p0 = 0.f, p1 = 0.f;
            #pragma unroll
            for (int r = 0; r < 4; ++r) {
                float s0 = acc[rt][0][r] + fi0 + bfv0;
                float s1 = acc[rt][1][r] + fi1 + bfv1;
                p0 += cv0[r] * __builtin_amdgcn_rcpf(1.f + __expf(-s0));
                p1 += cv1[r] * __builtin_amdgcn_rcpf(1.f + __expf(-s1));
            }
            // pair lanes g <-> g^1 hold k 0..3 / 4..7 of the same node
            p0 += __shfl_xor(p0, 16, 64);
            p1 += __shfl_xor(p1, 16, 64);
            if ((g & 1) == 0 && ok2[rt]) {
                float* orow = out + gns2[rt] * (4 * HSZ) + 3 * HSZ + col0;
                orow[0] = p0;
                orow[16] = p1;
            }
        }
    }
}

extern "C" void kernel_launch(void* const* d_in, const int* in_sizes, int n_in,
                              void* d_out, int out_size, void* d_ws, size_t ws_size,
                              hipStream_t stream) {
    const float* h       = (const float*)d_in[0];
    const float* c       = (const float*)d_in[1];
    const float* f_input = (const float*)d_in[2];
    const int*   type_id = (const int*)d_in[3];
    const float* U_iou   = (const float*)d_in[4];
    const float* b_iou   = (const float*)d_in[5];
    const float* U_f     = (const float*)d_in[6];
    const float* b_f     = (const float*)d_in[7];
    float* out = (float*)d_out;

    char* ws = (char*)d_ws;
    int* ws_i = (int*)ws;
    int* perm = (int*)(ws + WS_PERM_OFF);
    bf16* preUf = (bf16*)(ws + WS_PREUF_OFF);
    bf16* preUiou = (bf16*)(ws + WS_PREUIOU_OFF);

    hipMemsetAsync(ws, 0, 128, stream);
    k_swz    <<<(T_TYPES * HSZ * HSZ + T_TYPES * HSZ * 3 * HSZ) / 256, 256, 0, stream>>>(U_f, U_iou, preUf, preUiou);
    k_count  <<<N_NODES / 256, 256, 0, stream>>>(type_id, ws_i);
    k_offsets<<<1, 64, 0, stream>>>(ws_i);
    k_scatter<<<N_NODES / 256, 256, 0, stream>>>(type_id, ws_i, perm);

    k_main<<<N_NODES / TM + T_TYPES, 512, 0, stream>>>(h, c, f_input, b_iou, b_f,
                                                       perm, ws_i, preUf, preUiou, out);
}